// Round 1
// baseline (37.043 us; speedup 1.0000x reference)
//
#include <hip/hip_runtime.h>

#define BB 512
#define DD 128

__global__ void tl_zero(float* ws) {
  ws[0] = 0.0f;
  ws[1] = 0.0f;
}

__global__ __launch_bounds__(256) void tl_main(const float* __restrict__ emb,
                                               const int* __restrict__ labels,
                                               float* __restrict__ ws) {
  __shared__ float drow[BB];
  __shared__ int   lab[BB];
  __shared__ float ei[DD];
  __shared__ float redA[4], redB[4], redC[4], redL[4];
  __shared__ int   poslist[BB];
  __shared__ int   npos_s;

  const int i    = blockIdx.x;
  const int t    = threadIdx.x;
  const int lane = t & 63;
  const int wave = t >> 6;

  if (t == 0) npos_s = 0;
  lab[t]       = labels[t];
  lab[t + 256] = labels[t + 256];
  if (t < DD / 4)
    reinterpret_cast<float4*>(ei)[t] =
        reinterpret_cast<const float4*>(emb + (size_t)i * DD)[t];
  __syncthreads();

  const int lab_i = lab[i];

  // --- dist row: d[c] = ||e_i - e_c||^2, diagonal zeroed; also collect positives
  #pragma unroll
  for (int s = 0; s < 2; ++s) {
    const int c = t + s * 256;
    const float4* er = reinterpret_cast<const float4*>(emb + (size_t)c * DD);
    float acc = 0.f;
    #pragma unroll
    for (int k = 0; k < DD / 4; ++k) {
      float4 v = er[k];
      float4 u = reinterpret_cast<const float4*>(ei)[k];
      float d0 = u.x - v.x, d1 = u.y - v.y, d2 = u.z - v.z, d3 = u.w - v.w;
      acc = fmaf(d0, d0, acc);
      acc = fmaf(d1, d1, acc);
      acc = fmaf(d2, d2, acc);
      acc = fmaf(d3, d3, acc);
    }
    drow[c] = (c == i) ? 0.0f : acc;
    if (c != i && lab[c] == lab_i) {
      int idx = atomicAdd(&npos_s, 1);
      poslist[idx] = c;
    }
  }
  __syncthreads();

  // --- row max / min reductions
  const float v0 = drow[t], v1 = drow[t + 256];
  float lmax = fmaxf(v0, v1);
  float lmin = fminf(v0, v1);
  #pragma unroll
  for (int off = 32; off; off >>= 1) {
    lmax = fmaxf(lmax, __shfl_xor(lmax, off));
    lmin = fminf(lmin, __shfl_xor(lmin, off));
  }
  if (lane == 0) { redA[wave] = lmax; redB[wave] = lmin; }
  __syncthreads();
  const float row_max = fmaxf(fmaxf(redA[0], redA[1]), fmaxf(redA[2], redA[3]));
  const float row_min = fminf(fminf(redB[0], redB[1]), fminf(redB[2], redB[3]));

  // --- neg_inside: shifted masked max over negatives (matches reference trick)
  float ni = 0.0f;
  if (lab[t] != lab_i)       ni = fmaxf(ni, v0 - row_min);
  if (lab[t + 256] != lab_i) ni = fmaxf(ni, v1 - row_min);
  #pragma unroll
  for (int off = 32; off; off >>= 1) ni = fmaxf(ni, __shfl_xor(ni, off));
  if (lane == 0) redC[wave] = ni;
  __syncthreads();
  const float neg_inside =
      fmaxf(fmaxf(redC[0], redC[1]), fmaxf(redC[2], redC[3])) + row_min;

  // --- per positive j: masked min over candidates (one wave per j)
  const int npos = npos_s;
  float lpart = 0.0f;
  for (int p = wave; p < npos; p += 4) {
    const int j = poslist[p];
    const float thr = drow[j];
    float mn = 0.0f;          // masked-out entries contribute 0 (c=i always masked out)
    bool found = false;
    #pragma unroll
    for (int s = 0; s < 8; ++s) {
      const int c = lane + s * 64;
      const float dc = drow[c];
      if (lab[c] != lab_i && dc > thr) {
        mn = fminf(mn, dc - row_max);
        found = true;
      }
    }
    #pragma unroll
    for (int off = 32; off; off >>= 1) mn = fminf(mn, __shfl_xor(mn, off));
    const bool any = (__ballot(found) != 0ULL);
    if (lane == 0) {
      const float shn = any ? (mn + row_max) : neg_inside;
      lpart += fmaxf(1.0f + thr - shn, 0.0f);
    }
  }
  if (lane == 0) redL[wave] = lpart;
  __syncthreads();
  if (t == 0) {
    atomicAdd(&ws[0], redL[0] + redL[1] + redL[2] + redL[3]);
    atomicAdd(&ws[1], (float)npos);
  }
}

__global__ void tl_final(const float* __restrict__ ws, float* __restrict__ out) {
  out[0] = ws[0] / ws[1];
}

extern "C" void kernel_launch(void* const* d_in, const int* in_sizes, int n_in,
                              void* d_out, int out_size, void* d_ws, size_t ws_size,
                              hipStream_t stream) {
  const float* emb    = (const float*)d_in[0];
  const int*   labels = (const int*)d_in[1];
  float*       out    = (float*)d_out;
  float*       ws     = (float*)d_ws;

  tl_zero<<<1, 1, 0, stream>>>(ws);
  tl_main<<<BB, 256, 0, stream>>>(emb, labels, ws);
  tl_final<<<1, 1, 0, stream>>>(ws, out);
}

// Round 2
// 15.038 us; speedup vs baseline: 2.4634x; 2.4634x over previous
//
#include <hip/hip_runtime.h>

#define BB 512
#define DD 128

__global__ __launch_bounds__(256) void tl_main(const float* __restrict__ emb,
                                               const int* __restrict__ labels,
                                               float* __restrict__ ws) {
  __shared__ float drow[BB];
  __shared__ int   lab[BB];
  __shared__ float ei[DD];
  __shared__ float redA[4], redB[4], redC[4], redL[4];
  __shared__ int   poslist[BB];
  __shared__ int   npos_s;

  const int i    = blockIdx.x;
  const int t    = threadIdx.x;
  const int lane = t & 63;
  const int wave = t >> 6;

  if (t == 0) npos_s = 0;
  lab[t]       = labels[t];
  lab[t + 256] = labels[t + 256];
  if (t < DD / 4)
    reinterpret_cast<float4*>(ei)[t] =
        reinterpret_cast<const float4*>(emb + (size_t)i * DD)[t];
  __syncthreads();

  const int lab_i = lab[i];

  // --- dist row, coalesced: 4 lanes cooperate on one candidate.
  // Per wave-load: 16 candidates x 64B contiguous = 16 fully-used lines.
  const int sub = t & 3;   // lane within 4-group
  const int cid = t >> 2;  // candidate within tile [0,64)
  const float4* eis = reinterpret_cast<const float4*>(ei);
  #pragma unroll
  for (int s = 0; s < 8; ++s) {
    const int c = s * 64 + cid;
    const float4* er = reinterpret_cast<const float4*>(emb + (size_t)c * DD);
    float acc = 0.f;
    #pragma unroll
    for (int q = 0; q < 8; ++q) {
      const int k = sub + q * 4;
      float4 v = er[k];
      float4 u = eis[k];
      float d0 = u.x - v.x, d1 = u.y - v.y, d2 = u.z - v.z, d3 = u.w - v.w;
      acc = fmaf(d0, d0, acc);
      acc = fmaf(d1, d1, acc);
      acc = fmaf(d2, d2, acc);
      acc = fmaf(d3, d3, acc);
    }
    acc += __shfl_xor(acc, 1);
    acc += __shfl_xor(acc, 2);
    if (sub == 0) {
      drow[c] = (c == i) ? 0.0f : acc;
      if (c != i && lab[c] == lab_i) {
        int idx = atomicAdd(&npos_s, 1);  // LDS atomic, cheap
        poslist[idx] = c;
      }
    }
  }
  __syncthreads();

  // --- row max / min reductions
  const float v0 = drow[t], v1 = drow[t + 256];
  float lmax = fmaxf(v0, v1);
  float lmin = fminf(v0, v1);
  #pragma unroll
  for (int off = 32; off; off >>= 1) {
    lmax = fmaxf(lmax, __shfl_xor(lmax, off));
    lmin = fminf(lmin, __shfl_xor(lmin, off));
  }
  if (lane == 0) { redA[wave] = lmax; redB[wave] = lmin; }
  __syncthreads();
  const float row_max = fmaxf(fmaxf(redA[0], redA[1]), fmaxf(redA[2], redA[3]));
  const float row_min = fminf(fminf(redB[0], redB[1]), fminf(redB[2], redB[3]));

  // --- neg_inside: shifted masked max over negatives (matches reference trick)
  float ni = 0.0f;
  if (lab[t] != lab_i)       ni = fmaxf(ni, v0 - row_min);
  if (lab[t + 256] != lab_i) ni = fmaxf(ni, v1 - row_min);
  #pragma unroll
  for (int off = 32; off; off >>= 1) ni = fmaxf(ni, __shfl_xor(ni, off));
  if (lane == 0) redC[wave] = ni;
  __syncthreads();
  const float neg_inside =
      fmaxf(fmaxf(redC[0], redC[1]), fmaxf(redC[2], redC[3])) + row_min;

  // --- per positive j: masked min over candidates (one wave per j)
  const int npos = npos_s;
  float lpart = 0.0f;
  for (int p = wave; p < npos; p += 4) {
    const int j = poslist[p];
    const float thr = drow[j];
    float mn = 0.0f;  // masked-out entries contribute 0 (c=i always masked out)
    bool found = false;
    #pragma unroll
    for (int s = 0; s < 8; ++s) {
      const int c = lane + s * 64;
      const float dc = drow[c];
      if (lab[c] != lab_i && dc > thr) {
        mn = fminf(mn, dc - row_max);
        found = true;
      }
    }
    #pragma unroll
    for (int off = 32; off; off >>= 1) mn = fminf(mn, __shfl_xor(mn, off));
    const bool any = (__ballot(found) != 0ULL);
    if (lane == 0) {
      const float shn = any ? (mn + row_max) : neg_inside;
      lpart += fmaxf(1.0f + thr - shn, 0.0f);
    }
  }
  if (lane == 0) redL[wave] = lpart;
  __syncthreads();

  // --- per-row outputs (no global atomics)
  if (t == 0) {
    ws[i]      = redL[0] + redL[1] + redL[2] + redL[3];
    ws[BB + i] = (float)npos;
  }
}

__global__ __launch_bounds__(512) void tl_reduce(const float* __restrict__ ws,
                                                 float* __restrict__ out) {
  __shared__ float sl[8], sn[8];
  const int t = threadIdx.x, lane = t & 63, wave = t >> 6;
  float l = ws[t];
  float n = ws[BB + t];
  #pragma unroll
  for (int off = 32; off; off >>= 1) {
    l += __shfl_xor(l, off);
    n += __shfl_xor(n, off);
  }
  if (lane == 0) { sl[wave] = l; sn[wave] = n; }
  __syncthreads();
  if (t == 0) {
    float L = 0.f, N = 0.f;
    #pragma unroll
    for (int w = 0; w < 8; ++w) { L += sl[w]; N += sn[w]; }
    out[0] = L / N;
  }
}

extern "C" void kernel_launch(void* const* d_in, const int* in_sizes, int n_in,
                              void* d_out, int out_size, void* d_ws, size_t ws_size,
                              hipStream_t stream) {
  const float* emb    = (const float*)d_in[0];
  const int*   labels = (const int*)d_in[1];
  float*       out    = (float*)d_out;
  float*       ws     = (float*)d_ws;

  tl_main<<<BB, 256, 0, stream>>>(emb, labels, ws);
  tl_reduce<<<1, 512, 0, stream>>>(ws, out);
}

// Round 3
// 14.238 us; speedup vs baseline: 2.6017x; 1.0562x over previous
//
#include <hip/hip_runtime.h>

#define BB 512
#define DD 128
#define NBLK 256
#define MAXPOS 128

__global__ __launch_bounds__(512) void tl_main(const float* __restrict__ emb,
                                               const int* __restrict__ labels,
                                               float* __restrict__ ws) {
  __shared__ float drow[2][BB];
  __shared__ int   lab[BB];
  __shared__ float redM[2][4], redm[2][4], redN[2][4], redL[2][4];
  __shared__ int   poslist[2][MAXPOS];
  __shared__ int   npos_s[2];

  const int bid  = blockIdx.x;
  const int t    = threadIdx.x;
  const int lane = t & 63;
  const int wave = t >> 6;   // 0..7
  const int wrow = wave >> 2;  // row this wave reduces (0/1)
  const int wsub = wave & 3;   // wave index within the row group
  const int sub  = t & 3;      // lane within 4-group (dist phase)
  const int cid  = t >> 2;     // candidate id within pass [0,128)
  const int r0   = bid * 2;    // global rows r0, r0+1

  if (t < 2) npos_s[t] = 0;
  lab[t] = labels[t];
  __syncthreads();

  const int lab0 = lab[r0], lab1 = lab[r0 + 1];

  // --- anchor slices into registers (each lane: k = sub + 4q, q=0..7)
  float4 u0[8], u1[8];
  {
    const float4* e0 = reinterpret_cast<const float4*>(emb) + (size_t)r0 * (DD / 4);
    const float4* e1 = e0 + (DD / 4);
    #pragma unroll
    for (int q = 0; q < 8; ++q) {
      u0[q] = e0[sub + q * 4];
      u1[q] = e1[sub + q * 4];
    }
  }
  float sq0 = 0.f, sq1 = 0.f;
  #pragma unroll
  for (int q = 0; q < 8; ++q) {
    sq0 = fmaf(u0[q].x, u0[q].x, sq0); sq0 = fmaf(u0[q].y, u0[q].y, sq0);
    sq0 = fmaf(u0[q].z, u0[q].z, sq0); sq0 = fmaf(u0[q].w, u0[q].w, sq0);
    sq1 = fmaf(u1[q].x, u1[q].x, sq1); sq1 = fmaf(u1[q].y, u1[q].y, sq1);
    sq1 = fmaf(u1[q].z, u1[q].z, sq1); sq1 = fmaf(u1[q].w, u1[q].w, sq1);
  }
  sq0 += __shfl_xor(sq0, 1); sq0 += __shfl_xor(sq0, 2);
  sq1 += __shfl_xor(sq1, 1); sq1 += __shfl_xor(sq1, 2);

  // --- dist rows via d2 = sq_r + sq_c - 2*dot (one emb read serves both rows)
  #pragma unroll
  for (int s = 0; s < 4; ++s) {
    const int c = s * 128 + cid;
    const float4* er = reinterpret_cast<const float4*>(emb) + (size_t)c * (DD / 4);
    float sqc = 0.f, dt0 = 0.f, dt1 = 0.f;
    #pragma unroll
    for (int q = 0; q < 8; ++q) {
      float4 v = er[sub + q * 4];
      sqc = fmaf(v.x, v.x, sqc); sqc = fmaf(v.y, v.y, sqc);
      sqc = fmaf(v.z, v.z, sqc); sqc = fmaf(v.w, v.w, sqc);
      dt0 = fmaf(v.x, u0[q].x, dt0); dt0 = fmaf(v.y, u0[q].y, dt0);
      dt0 = fmaf(v.z, u0[q].z, dt0); dt0 = fmaf(v.w, u0[q].w, dt0);
      dt1 = fmaf(v.x, u1[q].x, dt1); dt1 = fmaf(v.y, u1[q].y, dt1);
      dt1 = fmaf(v.z, u1[q].z, dt1); dt1 = fmaf(v.w, u1[q].w, dt1);
    }
    sqc += __shfl_xor(sqc, 1); sqc += __shfl_xor(sqc, 2);
    dt0 += __shfl_xor(dt0, 1); dt0 += __shfl_xor(dt0, 2);
    dt1 += __shfl_xor(dt1, 1); dt1 += __shfl_xor(dt1, 2);
    if (sub == 0) {
      const float d0v = (c == r0)     ? 0.f : fmaxf(sq0 + sqc - 2.f * dt0, 0.f);
      const float d1v = (c == r0 + 1) ? 0.f : fmaxf(sq1 + sqc - 2.f * dt1, 0.f);
      drow[0][c] = d0v;
      drow[1][c] = d1v;
      const int lc = lab[c];
      if (c != r0 && lc == lab0) {
        int x = atomicAdd(&npos_s[0], 1);
        poslist[0][x] = c;
      }
      if (c != r0 + 1 && lc == lab1) {
        int x = atomicAdd(&npos_s[1], 1);
        poslist[1][x] = c;
      }
    }
  }
  __syncthreads();

  // --- per-row reductions: waves [4r .. 4r+3] handle row r
  const int labr = (wrow == 0) ? lab0 : lab1;
  const int c0 = wsub * 128 + lane;
  const int c1 = c0 + 64;
  const float v0 = drow[wrow][c0], v1 = drow[wrow][c1];
  float lmax = fmaxf(v0, v1), lmin = fminf(v0, v1);
  #pragma unroll
  for (int off = 32; off; off >>= 1) {
    lmax = fmaxf(lmax, __shfl_xor(lmax, off));
    lmin = fminf(lmin, __shfl_xor(lmin, off));
  }
  if (lane == 0) { redM[wrow][wsub] = lmax; redm[wrow][wsub] = lmin; }
  __syncthreads();
  const float row_max =
      fmaxf(fmaxf(redM[wrow][0], redM[wrow][1]), fmaxf(redM[wrow][2], redM[wrow][3]));
  const float row_min =
      fminf(fminf(redm[wrow][0], redm[wrow][1]), fminf(redm[wrow][2], redm[wrow][3]));

  // neg_inside: shifted masked max over negatives
  float ni = 0.f;
  if (lab[c0] != labr) ni = fmaxf(ni, v0 - row_min);
  if (lab[c1] != labr) ni = fmaxf(ni, v1 - row_min);
  #pragma unroll
  for (int off = 32; off; off >>= 1) ni = fmaxf(ni, __shfl_xor(ni, off));
  if (lane == 0) redN[wrow][wsub] = ni;
  __syncthreads();
  const float neg_inside =
      fmaxf(fmaxf(redN[wrow][0], redN[wrow][1]), fmaxf(redN[wrow][2], redN[wrow][3])) +
      row_min;

  // --- per positive j: masked min over candidates (one wave per j, 4-way)
  const int npos = npos_s[wrow];
  float lpart = 0.f;
  for (int p = wsub; p < npos; p += 4) {
    const int j = poslist[wrow][p];
    const float thr = drow[wrow][j];
    float mn = 0.f;  // masked-out entries contribute 0 (c=i always masked out)
    bool found = false;
    #pragma unroll
    for (int s2 = 0; s2 < 8; ++s2) {
      const int c = lane + s2 * 64;
      const float dc = drow[wrow][c];
      if (lab[c] != labr && dc > thr) {
        mn = fminf(mn, dc - row_max);
        found = true;
      }
    }
    #pragma unroll
    for (int off = 32; off; off >>= 1) mn = fminf(mn, __shfl_xor(mn, off));
    const bool any = (__ballot(found) != 0ULL);
    if (lane == 0) {
      const float shn = any ? (mn + row_max) : neg_inside;
      lpart += fmaxf(1.0f + thr - shn, 0.f);
    }
  }
  if (lane == 0) redL[wrow][wsub] = lpart;
  __syncthreads();

  if (t == 0) {
    const float L = redL[0][0] + redL[0][1] + redL[0][2] + redL[0][3] +
                    redL[1][0] + redL[1][1] + redL[1][2] + redL[1][3];
    ws[bid] = L;
    ws[NBLK + bid] = (float)(npos_s[0] + npos_s[1]);
  }
}

__global__ __launch_bounds__(256) void tl_reduce(const float* __restrict__ ws,
                                                 float* __restrict__ out) {
  __shared__ float sl[4], sn[4];
  const int t = threadIdx.x, lane = t & 63, wave = t >> 6;
  float l = ws[t];
  float n = ws[NBLK + t];
  #pragma unroll
  for (int off = 32; off; off >>= 1) {
    l += __shfl_xor(l, off);
    n += __shfl_xor(n, off);
  }
  if (lane == 0) { sl[wave] = l; sn[wave] = n; }
  __syncthreads();
  if (t == 0) {
    out[0] = (sl[0] + sl[1] + sl[2] + sl[3]) / (sn[0] + sn[1] + sn[2] + sn[3]);
  }
}

extern "C" void kernel_launch(void* const* d_in, const int* in_sizes, int n_in,
                              void* d_out, int out_size, void* d_ws, size_t ws_size,
                              hipStream_t stream) {
  const float* emb    = (const float*)d_in[0];
  const int*   labels = (const int*)d_in[1];
  float*       out    = (float*)d_out;
  float*       ws     = (float*)d_ws;

  tl_main<<<NBLK, 512, 0, stream>>>(emb, labels, ws);
  tl_reduce<<<1, 256, 0, stream>>>(ws, out);
}